// Round 11
// baseline (272.967 us; speedup 1.0000x reference)
//
#include <hip/hip_runtime.h>
#include <math.h>

#define TLEN 512
#define NCH  128
#define KP   4
#define PMAXV 64
#define CMAXV 32
#define MINP 16
#define NSEQ 4096   // B*N = 32*128
#define OUTG ((size_t)NSEQ * KP * CMAXV * PMAXV)   // 33,554,432

// pad-per-8 for 16B (double2) LDS elements: breaks power-of-2 bank strides
#define PAD8(i) ((i) + ((i) >> 3))
#define ZP   290            // >= PAD8(255)+1 = 287
#define SEQP 520            // padded f32 sequence row

typedef float nfloat4 __attribute__((ext_vector_type(4)));

// Grid = 512 blocks; each block serially processes 2 groups of 4 sequences
// (batch stagger: batch-1 store drain overlaps batch-2 FFT). One wave per
// sequence within a group; twiddles computed once per block.
__global__ __launch_bounds__(256) void periodicity_kernel(
    const float* __restrict__ x,
    float* __restrict__ out_g,
    float* __restrict__ out_m,
    float* __restrict__ out_a)
{
    const int tid  = threadIdx.x;
    const int lane = tid & 63;
    const int w    = tid >> 6;          // wave id = local sequence id

    __shared__ float   seqf[4 * SEQP];
    __shared__ double2 Z[4 * ZP];
    __shared__ double2 W[256];          // W_512^j, j=0..255

    // ---- twiddle table, once per block ----
    {
        double ang = -6.283185307179586476925286766559 * (double)tid / (double)TLEN;
        double sv, cv;
        sincos(ang, &sv, &cv);
        W[tid] = make_double2(cv, sv);
    }

    for (int iter = 0; iter < 2; ++iter) {
        const int s0 = (blockIdx.x << 2) + iter * (NSEQ / 2);
        const int b  = s0 >> 7;
        const int n0 = s0 & (NCH - 1);

        if (iter) __syncthreads();      // all waves done reading seqf
        {
            const int col = tid & 3;
            const int t0  = tid >> 2;   // 0..63
            const float* base = x + (size_t)b * TLEN * NCH + n0 + col;
            #pragma unroll
            for (int it = 0; it < 8; ++it) {
                const int t = t0 + 64 * it;
                seqf[col * SEQP + t] = base[(size_t)t * NCH];
            }
        }
        __syncthreads();                // seqf (+W on iter 0) ready

        float*   sf = seqf + w * SEQP;
        double2* Zw = Z + w * ZP;

        // ---- pack z[t]=x[2t]+i*x[2t+1], bit-reverse (8-bit) ----
        #pragma unroll
        for (int u = 0; u < 4; ++u) {
            const int i = lane + 64 * u;
            const int r = (int)(__brev((unsigned)i) >> 24);   // 8-bit reverse
            const float2 p = ((const float2*)sf)[r];          // x[2r], x[2r+1]
            Zw[PAD8(i)] = make_double2((double)p.x, (double)p.y);
        }
        __builtin_amdgcn_wave_barrier();

        // ---- 8 radix-2 DIT stages over 256 complex pts ----
        for (int st = 1; st <= 8; ++st) {
            const int half = 1 << (st - 1);
            #pragma unroll
            for (int u = 0; u < 2; ++u) {
                const int j   = lane + 64 * u;            // butterfly id 0..127
                const int pos = j & (half - 1);
                const int i1  = ((j >> (st - 1)) << st) + pos;
                const int i2  = i1 + half;
                // W_256^(pos<<(8-st)) == W_512^(pos<<(9-st))
                const double2 wv = W[pos << (9 - st)];
                const double2 a  = Zw[PAD8(i1)];
                const double2 c  = Zw[PAD8(i2)];
                const double tr = wv.x * c.x - wv.y * c.y;
                const double ti = wv.x * c.y + wv.y * c.x;
                Zw[PAD8(i1)] = make_double2(a.x + tr, a.y + ti);
                Zw[PAD8(i2)] = make_double2(a.x - tr, a.y - ti);
            }
            __builtin_amdgcn_wave_barrier();
        }

        // ---- untangle to amp^2 in registers (bins 0..256) ----
        // E[k]=(Z[k]+conj(Z[256-k]))/2, O[k]=-i(Z[k]-conj(Z[256-k]))/2,
        // X[k]=E[k]+W_512^k*O[k];  X[256]=Re(Z0)-Im(Z0).
        double av[5];
        int    bins[5];
        #pragma unroll
        for (int u = 0; u < 4; ++u) {
            const int k = lane + 64 * u;
            const double2 zk = Zw[PAD8(k)];
            const double2 zm = Zw[PAD8((256 - k) & 255)];
            const double gr = 0.5 * (zk.x + zm.x);
            const double gi = 0.5 * (zk.y - zm.y);
            const double hr = 0.5 * (zk.y + zm.y);
            const double hi = 0.5 * (zm.x - zk.x);
            const double2 wv = W[k];
            const double xr = gr + wv.x * hr - wv.y * hi;
            const double xi = gi + wv.x * hi + wv.y * hr;
            av[u]   = (k == 0) ? 0.0 : (xr * xr + xi * xi);
            bins[u] = k;
        }
        av[4]   = -1.0;
        bins[4] = 256;
        if (lane == 0) {
            const double2 z0 = Zw[PAD8(0)];
            const double nyq = z0.x - z0.y;
            av[4] = nyq * nyq;
        }

        // ---- top-4, in registers (smallest-index tie-break) ----
        double bv[KP];
        int    bi[KP];
        #pragma unroll
        for (int q = 0; q < KP; ++q) {
            double v  = av[0];
            int    vi = bins[0];
            #pragma unroll
            for (int j = 1; j < 5; ++j)
                if (av[j] > v) { v = av[j]; vi = bins[j]; }
            #pragma unroll
            for (int off = 32; off > 0; off >>= 1) {
                const double ov = __shfl_xor(v, off, 64);
                const int    oi = __shfl_xor(vi, off, 64);
                if (ov > v || (ov == v && oi < vi)) { v = ov; vi = oi; }
            }
            bv[q] = v; bi[q] = vi;
            #pragma unroll
            for (int j = 0; j < 5; ++j)
                if (bins[j] == vi) av[j] = -1.0;
        }

        const int s = s0 + w;
        if (lane < KP) {
            // sqrt only for winners: identical bits to sqrt-then-select
            double v = lane == 0 ? bv[0] : lane == 1 ? bv[1] : lane == 2 ? bv[2] : bv[3];
            out_a[(size_t)s * KP + lane] = (float)sqrt(v);
        }

        float* og = out_g + (size_t)s * (KP * CMAXV * PMAXV);
        float* om = out_m + (size_t)s * (KP * CMAXV * PMAXV);
        const int pp   = (lane & 15) << 2;     // p offset 0..60 step 4
        const int crow = lane >> 4;            // 0..3

        // ---- merged store loop, k hoisted ----
        #pragma unroll
        for (int k = 0; k < KP; ++k) {
            int ki = bi[k] < 1 ? 1 : bi[k];
            int P  = TLEN / ki;
            P = P < MINP ? MINP : (P > PMAXV ? PMAXV : P);
            const int cyc  = TLEN / P;         // 8..32
            const int base = TLEN - cyc * P;

            nfloat4 mrow;
            mrow.x = (pp     < P) ? 1.f : 0.f;
            mrow.y = (pp + 1 < P) ? 1.f : 0.f;
            mrow.z = (pp + 2 < P) ? 1.f : 0.f;
            mrow.w = (pp + 3 < P) ? 1.f : 0.f;

            float* ogk = og + k * (CMAXV * PMAXV) + pp;
            float* omk = om + k * (CMAXV * PMAXV) + pp;

            #pragma unroll
            for (int c8 = 0; c8 < 8; ++c8) {
                const int c = crow + 4 * c8;   // 0..31
                const bool live = c < cyc;
                nfloat4 m = (nfloat4)(0.f, 0.f, 0.f, 0.f);
                nfloat4 g = (nfloat4)(0.f, 0.f, 0.f, 0.f);
                if (live) {
                    m = mrow;
                    const int idx = base + c * P + pp;   // in-bounds if p < P
                    if (pp     < P) g.x = sf[idx];
                    if (pp + 1 < P) g.y = sf[idx + 1];
                    if (pp + 2 < P) g.z = sf[idx + 2];
                    if (pp + 3 < P) g.w = sf[idx + 3];
                }
                *(nfloat4*)(omk + c * PMAXV) = m;
                *(nfloat4*)(ogk + c * PMAXV) = g;
            }
        }
    }
}

extern "C" void kernel_launch(void* const* d_in, const int* in_sizes, int n_in,
                              void* d_out, int out_size, void* d_ws, size_t ws_size,
                              hipStream_t stream) {
    const float* x = (const float*)d_in[0];
    float* out = (float*)d_out;
    float* og = out;              // gathered: [B,N,K,Cmax,Pmax]
    float* om = out + OUTG;       // mask:     same shape
    float* oa = om + OUTG;        // kamp:     [B,N,K]

    periodicity_kernel<<<dim3(NSEQ / 8), dim3(256), 0, stream>>>(x, og, om, oa);
}

// Round 12
// 264.944 us; speedup vs baseline: 1.0303x; 1.0303x over previous
//
#include <hip/hip_runtime.h>
#include <math.h>

#define TLEN 512
#define NCH  128
#define KP   4
#define PMAXV 64
#define CMAXV 32
#define MINP 16
#define NSEQ 4096   // B*N = 32*128
#define OUTG ((size_t)NSEQ * KP * CMAXV * PMAXV)   // 33,554,432

// pad-per-8 for 16B (double2) LDS elements: breaks power-of-2 bank strides
#define PAD8(i) ((i) + ((i) >> 3))
#define ZP   290            // >= PAD8(255)+1 = 287
#define SEQP 520            // padded f32 sequence row

typedef float nfloat4 __attribute__((ext_vector_type(4)));

// One block = 4 sequences, one WAVE per sequence; one block barrier total.
// Real-input 512-pt FFT via 256-pt complex FFT + register untangle.
// Store phase: k-hoisted merged loop (params + mask row computed once per k).
// R11 note: 2-batch stagger at grid 512 regressed (2 blocks/CU < 4); this
// grid-1024 single-pass version is the measured optimum (269.1 us).
__global__ __launch_bounds__(256) void periodicity_kernel(
    const float* __restrict__ x,
    float* __restrict__ out_g,
    float* __restrict__ out_m,
    float* __restrict__ out_a)
{
    const int tid  = threadIdx.x;
    const int lane = tid & 63;
    const int w    = tid >> 6;          // wave id = local sequence id
    const int s0   = blockIdx.x << 2;   // first sequence of this block
    const int b    = s0 >> 7;           // all 4 seqs share b (4 | 128)
    const int n0   = s0 & (NCH - 1);    // multiple of 4

    __shared__ float   seqf[4 * SEQP];
    __shared__ double2 Z[4 * ZP];
    __shared__ double2 W[256];          // W_512^j, j=0..255

    // ---- cooperative load + in-block twiddle table ----
    {
        const int col = tid & 3;
        const int t0  = tid >> 2;       // 0..63
        const float* base = x + (size_t)b * TLEN * NCH + n0 + col;
        #pragma unroll
        for (int it = 0; it < 8; ++it) {
            const int t = t0 + 64 * it;
            seqf[col * SEQP + t] = base[(size_t)t * NCH];
        }
        double ang = -6.283185307179586476925286766559 * (double)tid / (double)TLEN;
        double sv, cv;
        sincos(ang, &sv, &cv);
        W[tid] = make_double2(cv, sv);
    }
    __syncthreads();                    // the ONLY block barrier

    float*   sf = seqf + w * SEQP;
    double2* Zw = Z + w * ZP;

    // ---- pack z[t]=x[2t]+i*x[2t+1], bit-reverse (8-bit), 4 pts/lane ----
    #pragma unroll
    for (int u = 0; u < 4; ++u) {
        const int i = lane + 64 * u;
        const int r = (int)(__brev((unsigned)i) >> 24);   // 8-bit reverse
        const float2 p = ((const float2*)sf)[r];          // x[2r], x[2r+1]
        Zw[PAD8(i)] = make_double2((double)p.x, (double)p.y);
    }
    __builtin_amdgcn_wave_barrier();

    // ---- 8 radix-2 DIT stages over 256 complex pts (2 butterflies/lane) ----
    for (int st = 1; st <= 8; ++st) {
        const int half = 1 << (st - 1);
        #pragma unroll
        for (int u = 0; u < 2; ++u) {
            const int j   = lane + 64 * u;                // butterfly id 0..127
            const int pos = j & (half - 1);
            const int i1  = ((j >> (st - 1)) << st) + pos;
            const int i2  = i1 + half;
            // W_256^(pos<<(8-st)) == W_512^(pos<<(9-st))
            const double2 wv = W[pos << (9 - st)];
            const double2 a  = Zw[PAD8(i1)];
            const double2 c  = Zw[PAD8(i2)];
            const double tr = wv.x * c.x - wv.y * c.y;
            const double ti = wv.x * c.y + wv.y * c.x;
            Zw[PAD8(i1)] = make_double2(a.x + tr, a.y + ti);
            Zw[PAD8(i2)] = make_double2(a.x - tr, a.y - ti);
        }
        __builtin_amdgcn_wave_barrier();
    }

    // ---- untangle to amp^2 straight into registers (bins 0..256) ----
    // E[k]=(Z[k]+conj(Z[256-k]))/2, O[k]=-i(Z[k]-conj(Z[256-k]))/2,
    // X[k]=E[k]+W_512^k*O[k];  X[256]=Re(Z0)-Im(Z0).
    double av[5];
    int    bins[5];
    #pragma unroll
    for (int u = 0; u < 4; ++u) {
        const int k = lane + 64 * u;
        const double2 zk = Zw[PAD8(k)];
        const double2 zm = Zw[PAD8((256 - k) & 255)];
        const double gr = 0.5 * (zk.x + zm.x);
        const double gi = 0.5 * (zk.y - zm.y);
        const double hr = 0.5 * (zk.y + zm.y);
        const double hi = 0.5 * (zm.x - zk.x);
        const double2 wv = W[k];
        const double xr = gr + wv.x * hr - wv.y * hi;
        const double xi = gi + wv.x * hi + wv.y * hr;
        av[u]   = (k == 0) ? 0.0 : (xr * xr + xi * xi);
        bins[u] = k;
    }
    av[4]   = -1.0;
    bins[4] = 256;
    if (lane == 0) {
        const double2 z0 = Zw[PAD8(0)];
        const double nyq = z0.x - z0.y;
        av[4] = nyq * nyq;
    }

    // ---- top-4, fully in registers (smallest-index tie-break) ----
    double bv[KP];
    int    bi[KP];
    #pragma unroll
    for (int q = 0; q < KP; ++q) {
        double v  = av[0];
        int    vi = bins[0];
        #pragma unroll
        for (int j = 1; j < 5; ++j)
            if (av[j] > v) { v = av[j]; vi = bins[j]; }
        #pragma unroll
        for (int off = 32; off > 0; off >>= 1) {
            const double ov = __shfl_xor(v, off, 64);
            const int    oi = __shfl_xor(vi, off, 64);
            if (ov > v || (ov == v && oi < vi)) { v = ov; vi = oi; }
        }
        bv[q] = v; bi[q] = vi;
        #pragma unroll
        for (int j = 0; j < 5; ++j)
            if (bins[j] == vi) av[j] = -1.0;
    }

    const int s = s0 + w;
    if (lane < KP) {
        // sqrt only for winners: identical bits to sqrt-then-select
        double v = lane == 0 ? bv[0] : lane == 1 ? bv[1] : lane == 2 ? bv[2] : bv[3];
        out_a[(size_t)s * KP + lane] = (float)sqrt(v);
    }

    float* og = out_g + (size_t)s * (KP * CMAXV * PMAXV);
    float* om = out_m + (size_t)s * (KP * CMAXV * PMAXV);
    const int pp   = (lane & 15) << 2;     // p offset 0..60 step 4
    const int crow = lane >> 4;            // 0..3

    // ---- merged store loop, k hoisted (params + mask row once per k) ----
    #pragma unroll
    for (int k = 0; k < KP; ++k) {
        int ki = bi[k] < 1 ? 1 : bi[k];
        int P  = TLEN / ki;
        P = P < MINP ? MINP : (P > PMAXV ? PMAXV : P);
        const int cyc  = TLEN / P;         // 8..32
        const int base = TLEN - cyc * P;

        // mask row pattern — identical for every live row of this k
        nfloat4 mrow;
        mrow.x = (pp     < P) ? 1.f : 0.f;
        mrow.y = (pp + 1 < P) ? 1.f : 0.f;
        mrow.z = (pp + 2 < P) ? 1.f : 0.f;
        mrow.w = (pp + 3 < P) ? 1.f : 0.f;

        float* ogk = og + k * (CMAXV * PMAXV) + pp;
        float* omk = om + k * (CMAXV * PMAXV) + pp;

        #pragma unroll
        for (int c8 = 0; c8 < 8; ++c8) {
            const int c = crow + 4 * c8;   // 0..31
            const bool live = c < cyc;
            nfloat4 m = (nfloat4)(0.f, 0.f, 0.f, 0.f);
            nfloat4 g = (nfloat4)(0.f, 0.f, 0.f, 0.f);
            if (live) {
                m = mrow;
                const int idx = base + c * P + pp;   // in-bounds whenever p < P
                if (pp     < P) g.x = sf[idx];
                if (pp + 1 < P) g.y = sf[idx + 1];
                if (pp + 2 < P) g.z = sf[idx + 2];
                if (pp + 3 < P) g.w = sf[idx + 3];
            }
            *(nfloat4*)(omk + c * PMAXV) = m;
            *(nfloat4*)(ogk + c * PMAXV) = g;
        }
    }
}

extern "C" void kernel_launch(void* const* d_in, const int* in_sizes, int n_in,
                              void* d_out, int out_size, void* d_ws, size_t ws_size,
                              hipStream_t stream) {
    const float* x = (const float*)d_in[0];
    float* out = (float*)d_out;
    float* og = out;              // gathered: [B,N,K,Cmax,Pmax]
    float* om = out + OUTG;       // mask:     same shape
    float* oa = om + OUTG;        // kamp:     [B,N,K]

    periodicity_kernel<<<dim3(NSEQ / 4), dim3(256), 0, stream>>>(x, og, om, oa);
}